// Round 12
// baseline (129.073 us; speedup 1.0000x reference)
//
#include <hip/hip_runtime.h>

// Problem constants (B=4, C=64, H=W=128, O=64, K=3, stride=1, pad=1, dil=1)
#define B_   4
#define C_   64
#define O_   64
#define H_   128
#define W_   128
#define HW_  (H_ * W_)
#define KK_  9
#define M_   18          // 2*KK offset channels

typedef short  short8   __attribute__((ext_vector_type(8)));
typedef float  floatx16 __attribute__((ext_vector_type(16)));
typedef unsigned short ushort4v __attribute__((ext_vector_type(4)));
typedef unsigned short ushort8v __attribute__((ext_vector_type(8)));

static __device__ __forceinline__ unsigned short f2bf(float f) {
    unsigned int u = __float_as_uint(f);
    u += 0x7FFFu + ((u >> 16) & 1u);     // round-to-nearest-even
    return (unsigned short)(u >> 16);
}
static __device__ __forceinline__ float bf2f(unsigned short s) {
    return __uint_as_float((unsigned int)s << 16);
}

#define ZERO16 {0.f,0.f,0.f,0.f,0.f,0.f,0.f,0.f,0.f,0.f,0.f,0.f,0.f,0.f,0.f,0.f}

// ---------------------------------------------------------------------------
// Prep (single launch):
//  blocks [0,512):   x -> xT[b][g16][y][x][c16] bf16 (8 consecutive channels
//                    at one corner = ONE aligned b128 load)
//  blocks [512,530): wtbf  = main-conv 32x32x16 B-fragments, lane order:
//                    frag (s*2+t): lane -> o = t*32+(lane&31),
//                    k = s*16+(lane>>5)*8+j  (k = tap*64 + c)
//  blocks [530,539): owtbf = offset-conv 32x32x16 B-fragments, lane order:
//                    frag s: lane -> m = lane&31 (pad>=18 -> 0),
//                    c = (s&3)*16+(lane>>5)*8+j, tap = s>>2
// ---------------------------------------------------------------------------
__global__ __launch_bounds__(256) void prep(
        const float* __restrict__ x, const float* __restrict__ w,
        const float* __restrict__ ow, unsigned short* __restrict__ xT,
        unsigned short* __restrict__ wtbf, unsigned short* __restrict__ owtbf) {
    const int blk = blockIdx.x;
    if (blk < 512) {
        __shared__ unsigned short T[128][72];   // [x][c], row padded to 72
        const int tid = threadIdx.x;
        const int y = blk & (H_ - 1);
        const int b = blk >> 7;
        const float* xby = x + (size_t)b * C_ * HW_ + y * W_;
        for (int i = tid; i < C_ * W_; i += 256) {
            const int c = i >> 7, xc = i & 127;
            T[xc][c] = f2bf(xby[(size_t)c * HW_ + xc]);
        }
        __syncthreads();
        unsigned short* dst = xT + (size_t)b * (4 * HW_ * 16) + y * (W_ * 16);
        for (int j = tid; j < 2048; j += 256) {
            const int g  = j >> 9;
            const int x8 = (j >> 2) & 127;
            const int c0 = (j & 3) * 4;
            const ushort4v pk = *(const ushort4v*)&T[x8][g * 16 + c0];
            *(ushort4v*)&dst[(size_t)g * (HW_ * 16) + x8 * 16 + c0] = pk;
        }
    } else if (blk < 530) {
        const int i = (blk - 512) * 256 + threadIdx.x;   // [0,4608)
        const int lane = i & 63, rest = i >> 6;          // rest = s*2+t
        const int t = rest & 1, s = rest >> 1;           // s in [0,36)
        const int o  = t * 32 + (lane & 31);
        const int kb = s * 16 + (lane >> 5) * 8;
        ushort8v pk;
        #pragma unroll
        for (int j = 0; j < 8; ++j) {
            const int k = kb + j;                        // k = tap*64 + c
            pk[j] = f2bf(w[o * 576 + (k & 63) * 9 + (k >> 6)]);
        }
        *(ushort8v*)&wtbf[(size_t)i * 8] = pk;
    } else {
        const int i = (blk - 530) * 256 + threadIdx.x;   // [0,2304)
        const int lane = i & 63, s = i >> 6;             // s in [0,36)
        const int m   = lane & 31;
        const int tap = s >> 2;
        const int cb  = (s & 3) * 16 + (lane >> 5) * 8;
        ushort8v pk;
        #pragma unroll
        for (int j = 0; j < 8; ++j)
            pk[j] = (m < M_) ? f2bf(ow[m * 576 + (cb + j) * 9 + tap])
                             : (unsigned short)0;
        *(ushort8v*)&owtbf[(size_t)i * 8] = pk;
    }
}

// ---------------------------------------------------------------------------
// Fused deformable conv, 32x32x16 MFMA, fully wave-autonomous.
// Block = ONE wave owning a 32-px row segment. ZERO __syncthreads.
//   A2 (offset conv): register-direct im2col A-frags from xT (1 predicated
//       b128 per k-step; integer taps, zero-pad via cndmask), 36 MFMAs
//       32x32x16 vs owtbf -> offs[m=lane&31][px=D-row] (+ob) in LDS.
//   B: per tap: geometry once (lane = its px, 2 k-octet halves share it);
//      per 16-k step: 4 corner b128 loads -> fp32 bilinear -> bf16 A-frag in
//      registers -> 2 MFMAs (o-tiles 0/1). 36 steps total. Weight stream is
//      amortized over 32 px (2x round-11).
//   Epilogue: D -> LDS [64 o][33] transpose -> coalesced stores (+bias).
// 32x32x16 layouts: D col=lane&31, row=(reg&3)+8*(reg>>2)+4*(lane>>5)
// [HW-verified]; A: m=lane&31, k=(lane>>5)*8+j; B: n=lane&31, same k.
// XCD banding (blockIdx%8 = XCD): XCD x owns rows [16x,16x+16) -> xT slice
// L2-resident per XCD.
// ---------------------------------------------------------------------------
__global__ __launch_bounds__(64, 4) void dcn_fused(
        const unsigned short* __restrict__ xT,
        const unsigned short* __restrict__ owtbf, const float* __restrict__ ob,
        const unsigned short* __restrict__ wtbf, const float* __restrict__ bias,
        float* __restrict__ out) {
    __shared__ float offs[M_][33];     // 2376 B  (wave-private)
    __shared__ float epw[64][33];      // 8448 B  (epilogue transpose)

    const int lane = threadIdx.x;      // block = 1 wave
    const int pxl  = lane & 31;        // this lane's pixel (m/n index)
    const int kh   = lane >> 5;        // k-octet half
    const int khOff = kh * 8;

    // XCD-banded remap (g%8 = XCD): XCD x -> rows [16x,16x+16)
    const int g    = blockIdx.x;
    const int xcd  = g & 7;
    const int slot = g >> 3;                   // [0,256) per XCD
    const int ho   = xcd * 16 + (slot >> 4);
    const int rest = slot & 15;
    const int b    = rest >> 2;
    const int wo_base = (rest & 3) << 5;       // 32-px segment

    const unsigned short* xTb = xT + (size_t)b * (4 * HW_ * 16);

    // ---------------- Phase A2: offset conv, register-direct im2col ---------
    floatx16 oa = ZERO16;
    for (int tap = 0; tap < 9; ++tap) {
        const int ky = tap / 3, kx = tap % 3;
        const int y    = ho - 1 + ky;
        const int xcol = wo_base - 1 + kx + pxl;
        const bool valid = ((unsigned)y < (unsigned)H_) &&
                           ((unsigned)xcol < (unsigned)W_);
        const int yc = min(max(y, 0), H_ - 1);
        const int xc = min(max(xcol, 0), W_ - 1);
        const int base = (yc * W_ + xc) * 16 + khOff;
        #pragma unroll
        for (int sl = 0; sl < 4; ++sl) {
            ushort8v q = {0, 0, 0, 0, 0, 0, 0, 0};
            if (valid)
                q = *(const ushort8v*)&xTb[(size_t)sl * (HW_ * 16) + base];
            const short8 af = *(const short8*)&q;
            const int s = tap * 4 + sl;
            const short8 bf = *(const short8*)&owtbf[(size_t)(s * 64 + lane) * 8];
            oa = __builtin_amdgcn_mfma_f32_32x32x16_bf16(af, bf, oa, 0, 0, 0);
        }
    }
    // offs[m][px] (+ offset bias); lane's column m = pxl, rows = D rows
    if (pxl < M_) {
        const float obm = ob[pxl];
        #pragma unroll
        for (int r = 0; r < 16; ++r) {
            const int px = (r & 3) + 8 * (r >> 2) + 4 * kh;
            offs[pxl][px] = oa[r] + obm;
        }
    }
    // single wave: DS program order + compiler lgkmcnt waits; no barrier

    // ---------------- Phase B: sample + MFMA (wave-autonomous) --------------
    floatx16 acc0 = ZERO16, acc1 = ZERO16;
    for (int tap = 0; tap < 9; ++tap) {
        const int ky = tap / 3, kx = tap % 3;
        const float offy = offs[2 * tap][pxl];
        const float offx = offs[2 * tap + 1][pxl];
        const float py  = (float)(ho - 1 + ky) + offy;
        const float pxx = (float)(wo_base - 1 + kx + pxl) + offx;
        const float fy = floorf(py), fx = floorf(pxx);
        const int y0 = (int)fy, x0 = (int)fx;
        const int y1 = y0 + 1,  x1 = x0 + 1;
        const float wy1 = py - fy,  wy0 = 1.f - wy1;
        const float wx1 = pxx - fx, wx0 = 1.f - wx1;
        const bool y0v = (unsigned)y0 < (unsigned)H_;
        const bool y1v = (unsigned)y1 < (unsigned)H_;
        const bool x0v = (unsigned)x0 < (unsigned)W_;
        const bool x1v = (unsigned)x1 < (unsigned)W_;
        const float w00 = (y0v && x0v) ? wy0 * wx0 : 0.f;
        const float w01 = (y0v && x1v) ? wy0 * wx1 : 0.f;
        const float w10 = (y1v && x0v) ? wy1 * wx0 : 0.f;
        const float w11 = (y1v && x1v) ? wy1 * wx1 : 0.f;
        const int ry0 = min(max(y0, 0), H_ - 1);
        const int ry1 = min(max(y1, 0), H_ - 1);
        const int cx0 = min(max(x0, 0), W_ - 1);
        const int cx1 = min(max(x1, 0), W_ - 1);
        const int a00 = (ry0 * W_ + cx0) * 16 + khOff;
        const int a01 = (ry0 * W_ + cx1) * 16 + khOff;
        const int a10 = (ry1 * W_ + cx0) * 16 + khOff;
        const int a11 = (ry1 * W_ + cx1) * 16 + khOff;
        #pragma unroll
        for (int sl = 0; sl < 4; ++sl) {
            const unsigned short* xp = xTb + (size_t)sl * (HW_ * 16);
            const ushort8v q00 = *(const ushort8v*)&xp[a00];
            const ushort8v q01 = *(const ushort8v*)&xp[a01];
            const ushort8v q10 = *(const ushort8v*)&xp[a10];
            const ushort8v q11 = *(const ushort8v*)&xp[a11];
            ushort8v pk;
            #pragma unroll
            for (int j = 0; j < 8; ++j)
                pk[j] = f2bf(bf2f(q00[j]) * w00 + bf2f(q01[j]) * w01
                           + bf2f(q10[j]) * w10 + bf2f(q11[j]) * w11);
            const short8 af = *(const short8*)&pk;
            const int s = tap * 4 + sl;
            const short8 bf0 = *(const short8*)
                &wtbf[(size_t)((s * 2 + 0) * 64 + lane) * 8];
            const short8 bf1 = *(const short8*)
                &wtbf[(size_t)((s * 2 + 1) * 64 + lane) * 8];
            acc0 = __builtin_amdgcn_mfma_f32_32x32x16_bf16(af, bf0, acc0, 0, 0, 0);
            acc1 = __builtin_amdgcn_mfma_f32_32x32x16_bf16(af, bf1, acc1, 0, 0, 0);
        }
    }

    // ---------------- Epilogue: LDS transpose, coalesced stores -------------
    #pragma unroll
    for (int r = 0; r < 16; ++r) {
        const int px = (r & 3) + 8 * (r >> 2) + 4 * kh;
        epw[pxl][px]      = acc0[r];       // o-tile 0: o = pxl
        epw[32 + pxl][px] = acc1[r];       // o-tile 1: o = 32 + pxl
    }
    const size_t obase = (size_t)b * O_ * HW_ + ho * W_ + wo_base;
    #pragma unroll
    for (int i = 0; i < 32; ++i) {
        const int o = i * 2 + kh;
        out[obase + (size_t)o * HW_ + pxl] = epw[o][pxl] + bias[o];
    }
}

// ---------------------------------------------------------------------------
extern "C" void kernel_launch(void* const* d_in, const int* in_sizes, int n_in,
                              void* d_out, int out_size, void* d_ws, size_t ws_size,
                              hipStream_t stream) {
    const float* x    = (const float*)d_in[0];  // [4,64,128,128]
    const float* ow   = (const float*)d_in[1];  // [18,64,3,3]
    const float* ob   = (const float*)d_in[2];  // [18]
    const float* w    = (const float*)d_in[3];  // [64,64,3,3]
    const float* bias = (const float*)d_in[4];  // [64]
    float* out = (float*)d_out;                 // [4,64,128,128]

    unsigned short* wtbf  = (unsigned short*)d_ws;      // 4608 lane-frags 73728 B
    unsigned short* owtbf = wtbf + 4608 * 8;            // 2304 lane-frags 36864 B
    unsigned short* xT    = owtbf + 2304 * 8;           // [4][4][HW][16]  8.39 MB

    prep<<<539, 256, 0, stream>>>(x, w, ow, xT, wtbf, owtbf);
    dcn_fused<<<B_ * H_ * (W_ / 32), 64, 0, stream>>>(xT, owtbf, ob, wtbf, bias, out);
}

// Round 13
// 113.348 us; speedup vs baseline: 1.1387x; 1.1387x over previous
//
#include <hip/hip_runtime.h>

// Problem constants (B=4, C=64, H=W=128, O=64, K=3, stride=1, pad=1, dil=1)
#define B_   4
#define C_   64
#define O_   64
#define H_   128
#define W_   128
#define HW_  (H_ * W_)
#define KK_  9
#define M_   18          // 2*KK offset channels

typedef short  short8   __attribute__((ext_vector_type(8)));
typedef float  floatx16 __attribute__((ext_vector_type(16)));
typedef unsigned short ushort4v __attribute__((ext_vector_type(4)));
typedef unsigned short ushort8v __attribute__((ext_vector_type(8)));

static __device__ __forceinline__ unsigned short f2bf(float f) {
    unsigned int u = __float_as_uint(f);
    u += 0x7FFFu + ((u >> 16) & 1u);     // round-to-nearest-even
    return (unsigned short)(u >> 16);
}
static __device__ __forceinline__ float bf2f(unsigned short s) {
    return __uint_as_float((unsigned int)s << 16);
}

#define ZERO16 {0.f,0.f,0.f,0.f,0.f,0.f,0.f,0.f,0.f,0.f,0.f,0.f,0.f,0.f,0.f,0.f}

// ---------------------------------------------------------------------------
// Prep (single launch) -- unchanged from round 12:
//  blocks [0,512):   x -> xT[b][g16][y][x][c16] bf16 (8 consecutive channels
//                    at one corner = ONE aligned b128 load)
//  blocks [512,530): wtbf  = main-conv 32x32x16 B-fragments, lane order:
//                    frag (s*2+t): lane -> o = t*32+(lane&31),
//                    k = s*16+(lane>>5)*8+j  (k = tap*64 + c)
//  blocks [530,539): owtbf = offset-conv 32x32x16 B-fragments, lane order:
//                    frag s: lane -> m = lane&31 (pad>=18 -> 0),
//                    c = (s&3)*16+(lane>>5)*8+j, tap = s>>2
// ---------------------------------------------------------------------------
__global__ __launch_bounds__(256) void prep(
        const float* __restrict__ x, const float* __restrict__ w,
        const float* __restrict__ ow, unsigned short* __restrict__ xT,
        unsigned short* __restrict__ wtbf, unsigned short* __restrict__ owtbf) {
    const int blk = blockIdx.x;
    if (blk < 512) {
        __shared__ unsigned short T[128][72];   // [x][c], row padded to 72
        const int tid = threadIdx.x;
        const int y = blk & (H_ - 1);
        const int b = blk >> 7;
        const float* xby = x + (size_t)b * C_ * HW_ + y * W_;
        for (int i = tid; i < C_ * W_; i += 256) {
            const int c = i >> 7, xc = i & 127;
            T[xc][c] = f2bf(xby[(size_t)c * HW_ + xc]);
        }
        __syncthreads();
        unsigned short* dst = xT + (size_t)b * (4 * HW_ * 16) + y * (W_ * 16);
        for (int j = tid; j < 2048; j += 256) {
            const int g  = j >> 9;
            const int x8 = (j >> 2) & 127;
            const int c0 = (j & 3) * 4;
            const ushort4v pk = *(const ushort4v*)&T[x8][g * 16 + c0];
            *(ushort4v*)&dst[(size_t)g * (HW_ * 16) + x8 * 16 + c0] = pk;
        }
    } else if (blk < 530) {
        const int i = (blk - 512) * 256 + threadIdx.x;   // [0,4608)
        const int lane = i & 63, rest = i >> 6;          // rest = s*2+t
        const int t = rest & 1, s = rest >> 1;           // s in [0,36)
        const int o  = t * 32 + (lane & 31);
        const int kb = s * 16 + (lane >> 5) * 8;
        ushort8v pk;
        #pragma unroll
        for (int j = 0; j < 8; ++j) {
            const int k = kb + j;                        // k = tap*64 + c
            pk[j] = f2bf(w[o * 576 + (k & 63) * 9 + (k >> 6)]);
        }
        *(ushort8v*)&wtbf[(size_t)i * 8] = pk;
    } else {
        const int i = (blk - 530) * 256 + threadIdx.x;   // [0,2304)
        const int lane = i & 63, s = i >> 6;             // s in [0,36)
        const int m   = lane & 31;
        const int tap = s >> 2;
        const int cb  = (s & 3) * 16 + (lane >> 5) * 8;
        ushort8v pk;
        #pragma unroll
        for (int j = 0; j < 8; ++j)
            pk[j] = (m < M_) ? f2bf(ow[m * 576 + (cb + j) * 9 + tap])
                             : (unsigned short)0;
        *(ushort8v*)&owtbf[(size_t)i * 8] = pk;
    }
}

// ---------------------------------------------------------------------------
// Fused deformable conv, 32x32x16 MFMA, wave-autonomous, 4-wave blocks.
// Block = full 128-px output row (b, ho); wave w owns px [32w, 32w+32).
// ZERO barriers: each wave uses only its own LDS regions (offs/epw[wslot]).
// The 4 waves share the CU's L1 for the same 3 xT input rows (round-12's
// one-wave blocks lost this: FETCH 5.5->14.7 MB) and write each out row
// 512B-dense (round-12 scattered 128B chunks: WRITE 16->56 MB).
//   A2: register-direct im2col A-frags from xT (predicated b128, integer
//       taps), 36 32x32x16 MFMAs vs owtbf -> offs[w][m][px] (+ob).
//   B: per tap geometry once; per 16-k step 4 corner b128 loads -> fp32
//      bilinear -> bf16 A-frag -> 2 MFMAs (o-tiles). Weight stream amortized
//      over 32 px.
//   Epilogue: D -> epw[w][64 o][33] -> coalesced stores (+bias).
// 32x32x16 layouts: D col=lane&31, row=(reg&3)+8*(reg>>2)+4*(lane>>5)
// [HW-verified]; A: m=lane&31, k=(lane>>5)*8+j; B: n=lane&31, same k.
// XCD banding (blockIdx%8 = XCD): XCD x owns rows [16x,16x+16) -> xT slice
// L2-resident per XCD.
// ---------------------------------------------------------------------------
__global__ __launch_bounds__(256, 2) void dcn_fused(
        const unsigned short* __restrict__ xT,
        const unsigned short* __restrict__ owtbf, const float* __restrict__ ob,
        const unsigned short* __restrict__ wtbf, const float* __restrict__ bias,
        float* __restrict__ out) {
    __shared__ float offs[4][M_][33];      //  9504 B (wave-private)
    __shared__ float epw[4][64][33];       // 33792 B (wave-private epilogue)

    const int tid   = threadIdx.x;
    const int lane  = tid & 63;
    const int wslot = __builtin_amdgcn_readfirstlane(tid >> 6);
    const int pxl   = lane & 31;           // lane's pixel within the wave tile
    const int kh    = lane >> 5;           // k-octet half
    const int khOff = kh * 8;

    // XCD-banded remap (g%8 = XCD): XCD x -> rows [16x,16x+16)
    const int g    = blockIdx.x;
    const int xcd  = g & 7;
    const int slot = g >> 3;                   // [0,64) per XCD
    const int ho   = xcd * 16 + (slot >> 2);
    const int b    = slot & 3;
    const int wo_base = wslot * 32;            // wave's 32-px segment

    const unsigned short* xTb = xT + (size_t)b * (4 * HW_ * 16);

    // ---------------- Phase A2: offset conv, register-direct im2col ---------
    floatx16 oa = ZERO16;
    for (int tap = 0; tap < 9; ++tap) {
        const int ky = tap / 3, kx = tap % 3;
        const int y    = ho - 1 + ky;
        const int xcol = wo_base - 1 + kx + pxl;
        const bool valid = ((unsigned)y < (unsigned)H_) &&
                           ((unsigned)xcol < (unsigned)W_);
        const int yc = min(max(y, 0), H_ - 1);
        const int xc = min(max(xcol, 0), W_ - 1);
        const int base = (yc * W_ + xc) * 16 + khOff;
        #pragma unroll
        for (int sl = 0; sl < 4; ++sl) {
            ushort8v q = {0, 0, 0, 0, 0, 0, 0, 0};
            if (valid)
                q = *(const ushort8v*)&xTb[(size_t)sl * (HW_ * 16) + base];
            const short8 af = *(const short8*)&q;
            const int s = tap * 4 + sl;
            const short8 bf = *(const short8*)&owtbf[(size_t)(s * 64 + lane) * 8];
            oa = __builtin_amdgcn_mfma_f32_32x32x16_bf16(af, bf, oa, 0, 0, 0);
        }
    }
    // offs[w][m][px] (+ offset bias); lane's column m = pxl, rows = D rows
    if (pxl < M_) {
        const float obm = ob[pxl];
        #pragma unroll
        for (int r = 0; r < 16; ++r) {
            const int px = (r & 3) + 8 * (r >> 2) + 4 * kh;
            offs[wslot][pxl][px] = oa[r] + obm;
        }
    }
    // wave-private LDS: DS program order + compiler lgkmcnt; no barrier

    // ---------------- Phase B: sample + MFMA (wave-autonomous) --------------
    floatx16 acc0 = ZERO16, acc1 = ZERO16;
    for (int tap = 0; tap < 9; ++tap) {
        const int ky = tap / 3, kx = tap % 3;
        const float offy = offs[wslot][2 * tap][pxl];
        const float offx = offs[wslot][2 * tap + 1][pxl];
        const float py  = (float)(ho - 1 + ky) + offy;
        const float pxx = (float)(wo_base - 1 + kx + pxl) + offx;
        const float fy = floorf(py), fx = floorf(pxx);
        const int y0 = (int)fy, x0 = (int)fx;
        const int y1 = y0 + 1,  x1 = x0 + 1;
        const float wy1 = py - fy,  wy0 = 1.f - wy1;
        const float wx1 = pxx - fx, wx0 = 1.f - wx1;
        const bool y0v = (unsigned)y0 < (unsigned)H_;
        const bool y1v = (unsigned)y1 < (unsigned)H_;
        const bool x0v = (unsigned)x0 < (unsigned)W_;
        const bool x1v = (unsigned)x1 < (unsigned)W_;
        const float w00 = (y0v && x0v) ? wy0 * wx0 : 0.f;
        const float w01 = (y0v && x1v) ? wy0 * wx1 : 0.f;
        const float w10 = (y1v && x0v) ? wy1 * wx0 : 0.f;
        const float w11 = (y1v && x1v) ? wy1 * wx1 : 0.f;
        const int ry0 = min(max(y0, 0), H_ - 1);
        const int ry1 = min(max(y1, 0), H_ - 1);
        const int cx0 = min(max(x0, 0), W_ - 1);
        const int cx1 = min(max(x1, 0), W_ - 1);
        const int a00 = (ry0 * W_ + cx0) * 16 + khOff;
        const int a01 = (ry0 * W_ + cx1) * 16 + khOff;
        const int a10 = (ry1 * W_ + cx0) * 16 + khOff;
        const int a11 = (ry1 * W_ + cx1) * 16 + khOff;
        #pragma unroll
        for (int sl = 0; sl < 4; ++sl) {
            const unsigned short* xp = xTb + (size_t)sl * (HW_ * 16);
            const ushort8v q00 = *(const ushort8v*)&xp[a00];
            const ushort8v q01 = *(const ushort8v*)&xp[a01];
            const ushort8v q10 = *(const ushort8v*)&xp[a10];
            const ushort8v q11 = *(const ushort8v*)&xp[a11];
            ushort8v pk;
            #pragma unroll
            for (int j = 0; j < 8; ++j)
                pk[j] = f2bf(bf2f(q00[j]) * w00 + bf2f(q01[j]) * w01
                           + bf2f(q10[j]) * w10 + bf2f(q11[j]) * w11);
            const short8 af = *(const short8*)&pk;
            const int s = tap * 4 + sl;
            const short8 bf0 = *(const short8*)
                &wtbf[(size_t)((s * 2 + 0) * 64 + lane) * 8];
            const short8 bf1 = *(const short8*)
                &wtbf[(size_t)((s * 2 + 1) * 64 + lane) * 8];
            acc0 = __builtin_amdgcn_mfma_f32_32x32x16_bf16(af, bf0, acc0, 0, 0, 0);
            acc1 = __builtin_amdgcn_mfma_f32_32x32x16_bf16(af, bf1, acc1, 0, 0, 0);
        }
    }

    // ---------------- Epilogue: per-wave LDS transpose, coalesced stores ----
    #pragma unroll
    for (int r = 0; r < 16; ++r) {
        const int px = (r & 3) + 8 * (r >> 2) + 4 * kh;
        epw[wslot][pxl][px]      = acc0[r];    // o-tile 0: o = pxl
        epw[wslot][32 + pxl][px] = acc1[r];    // o-tile 1: o = 32 + pxl
    }
    const size_t obase = (size_t)b * O_ * HW_ + ho * W_ + wo_base;
    #pragma unroll
    for (int i = 0; i < 32; ++i) {
        const int o = i * 2 + kh;
        out[obase + (size_t)o * HW_ + pxl] = epw[wslot][o][pxl] + bias[o];
    }
}

// ---------------------------------------------------------------------------
extern "C" void kernel_launch(void* const* d_in, const int* in_sizes, int n_in,
                              void* d_out, int out_size, void* d_ws, size_t ws_size,
                              hipStream_t stream) {
    const float* x    = (const float*)d_in[0];  // [4,64,128,128]
    const float* ow   = (const float*)d_in[1];  // [18,64,3,3]
    const float* ob   = (const float*)d_in[2];  // [18]
    const float* w    = (const float*)d_in[3];  // [64,64,3,3]
    const float* bias = (const float*)d_in[4];  // [64]
    float* out = (float*)d_out;                 // [4,64,128,128]

    unsigned short* wtbf  = (unsigned short*)d_ws;      // 4608 lane-frags 73728 B
    unsigned short* owtbf = wtbf + 4608 * 8;            // 2304 lane-frags 36864 B
    unsigned short* xT    = owtbf + 2304 * 8;           // [4][4][HW][16]  8.39 MB

    prep<<<539, 256, 0, stream>>>(x, w, ow, xT, wtbf, owtbf);
    dcn_fused<<<B_ * H_, 256, 0, stream>>>(xT, owtbf, ob, wtbf, bias, out);
}